// Round 1
// baseline (65.059 us; speedup 1.0000x reference)
//
#include <hip/hip_runtime.h>

// out[b,o] = sum_j sum_d coeff[o*128+j, d] * x[b,j]^d
// == GEMM: out[M=8192, N=128] = P[M, K=512] * W[N, K=512]^T
//   where k = j*4+d, W[o,k] = coeff[o*512+k] (coeff is already [128,512] row-major),
//   P[b,k] = x[b, k>>2] ^ (k&3)  (computed on the fly during LDS staging).

#define BATCH   8192
#define IN_DIM  128
#define OUT_DIM 128
#define KDIM    512          // IN_DIM * 4
#define M_BLK   32
#define N_BLK   64
#define BK      64           // k per LDS stage (2 MFMA k-steps)
#define LDSS    72           // 64 + 8 pad (shorts) -> 144B row stride, 16B aligned, 2-way banks

typedef __attribute__((ext_vector_type(8))) short bf16x8;
typedef __attribute__((ext_vector_type(4))) float f32x4;
typedef __attribute__((ext_vector_type(8))) unsigned short u16x8;

__device__ inline unsigned short f2bf(float f) {
    union { float f; unsigned int u; } v; v.f = f;
    unsigned int u = v.u;
    u += 0x7FFFu + ((u >> 16) & 1u);   // round-to-nearest-even
    return (unsigned short)(u >> 16);
}

__global__ __launch_bounds__(256) void kan_mfma(const float* __restrict__ x,
                                                const float* __restrict__ coeff,
                                                float* __restrict__ out) {
    __shared__ __align__(16) unsigned short A_lds[M_BLK * LDSS];
    __shared__ __align__(16) unsigned short W_lds[N_BLK * LDSS];

    const int t    = threadIdx.x;
    const int w    = t >> 6;          // wave 0..3
    const int lane = t & 63;
    const int quad = lane >> 4;
    const int lr   = lane & 15;
    const int m0   = blockIdx.x * M_BLK;
    const int n0   = blockIdx.y * N_BLK;

    f32x4 acc0 = {0.f, 0.f, 0.f, 0.f};
    f32x4 acc1 = {0.f, 0.f, 0.f, 0.f};

    // A staging: 32 rows x 16 j (float2 per thread)
    const int am  = t >> 3;           // 0..31
    const int ajp = t & 7;            // float2 slot 0..7
    // W staging: 64 rows x 64 k (16 floats per thread)
    const int wn    = t >> 2;         // 0..63
    const int wpart = t & 3;          // 0..3

    for (int stage = 0; stage < KDIM / BK; ++stage) {
        const int k0 = stage * BK;
        const int j0 = k0 >> 2;

        // ---- global loads (before barrier, hide latency) ----
        const float2 xv = *(const float2*)&x[(m0 + am) * IN_DIM + j0 + ajp * 2];
        const float* cbase = &coeff[(n0 + wn) * KDIM + k0 + wpart * 16];
        const float4 c0 = *(const float4*)(cbase + 0);
        const float4 c1 = *(const float4*)(cbase + 4);
        const float4 c2 = *(const float4*)(cbase + 8);
        const float4 c3 = *(const float4*)(cbase + 12);

        __syncthreads();   // previous stage's compute done before overwrite

        // ---- A: powers {1, x, x^2, x^3} for two x values -> 8 bf16 ----
        {
            u16x8 av;
            const float xa = xv.x, xb = xv.y;
            av[0] = 0x3F80u;      av[1] = f2bf(xa);
            av[2] = f2bf(xa*xa);  av[3] = f2bf(xa*xa*xa);
            av[4] = 0x3F80u;      av[5] = f2bf(xb);
            av[6] = f2bf(xb*xb);  av[7] = f2bf(xb*xb*xb);
            *(u16x8*)&A_lds[am * LDSS + ajp * 8] = av;
        }
        // ---- W: 16 fp32 -> 16 bf16 ----
        {
            u16x8 wv0, wv1;
            wv0[0]=f2bf(c0.x); wv0[1]=f2bf(c0.y); wv0[2]=f2bf(c0.z); wv0[3]=f2bf(c0.w);
            wv0[4]=f2bf(c1.x); wv0[5]=f2bf(c1.y); wv0[6]=f2bf(c1.z); wv0[7]=f2bf(c1.w);
            wv1[0]=f2bf(c2.x); wv1[1]=f2bf(c2.y); wv1[2]=f2bf(c2.z); wv1[3]=f2bf(c2.w);
            wv1[4]=f2bf(c3.x); wv1[5]=f2bf(c3.y); wv1[6]=f2bf(c3.z); wv1[7]=f2bf(c3.w);
            *(u16x8*)&W_lds[wn * LDSS + wpart * 16 + 0] = wv0;
            *(u16x8*)&W_lds[wn * LDSS + wpart * 16 + 8] = wv1;
        }
        __syncthreads();

        // ---- MFMA: 2 k-steps of 32, tiles (rows 0-15 and 16-31) x (cols w*16..) ----
        #pragma unroll
        for (int s = 0; s < 2; ++s) {
            const int ko = s * 32 + quad * 8;
            const bf16x8 a0 = *(const bf16x8*)&A_lds[lr        * LDSS + ko];
            const bf16x8 a1 = *(const bf16x8*)&A_lds[(16 + lr) * LDSS + ko];
            const bf16x8 bm = *(const bf16x8*)&W_lds[(w*16+lr) * LDSS + ko];
            acc0 = __builtin_amdgcn_mfma_f32_16x16x32_bf16(a0, bm, acc0, 0, 0, 0);
            acc1 = __builtin_amdgcn_mfma_f32_16x16x32_bf16(a1, bm, acc1, 0, 0, 0);
        }
    }

    // ---- epilogue: C/D layout col=lane&15, row=quad*4+reg ----
    const int col = n0 + w * 16 + lr;
    #pragma unroll
    for (int r = 0; r < 4; ++r) {
        out[(m0 +      quad * 4 + r) * OUT_DIM + col] = acc0[r];
        out[(m0 + 16 + quad * 4 + r) * OUT_DIM + col] = acc1[r];
    }
}

extern "C" void kernel_launch(void* const* d_in, const int* in_sizes, int n_in,
                              void* d_out, int out_size, void* d_ws, size_t ws_size,
                              hipStream_t stream) {
    const float* x     = (const float*)d_in[0];   // [8192, 128] fp32
    const float* coeff = (const float*)d_in[1];   // [16384, 4] fp32 == [128, 512]
    float* out = (float*)d_out;                   // [8192, 128] fp32

    dim3 grid(BATCH / M_BLK, OUT_DIM / N_BLK);    // 256 x 2 = 512 blocks
    kan_mfma<<<grid, 256, 0, stream>>>(x, coeff, out);
}